// Round 7
// baseline (917.937 us; speedup 1.0000x reference)
//
#include <hip/hip_runtime.h>
#include <stdint.h>

#define E_    16
#define TOPK  2
#define D_    1024
#define H_    1024
#define SH_   2048
#define NTOK  4096
#define BK    32      // K-step (u16 elements); tile rows are 64B
#define NDESC 80      // max expert chunks: 8192/128 + 16 partials
#define RTOK  16      // router tokens per block
#define NRBLK (NTOK / RTOK)         // 256 router blocks
#define NSHUP (NTOK/128 * SH_/128)  // 512 shared-up blocks (gy=16)
#define NRTUP (NDESC * H_/128)      // 640 routed-up blocks (gy=8)
#define NSHDN (NTOK/128 * D_/128)   // 256 shared-down blocks (gy=8)
#define NRTDN (NDESC * D_/128)      // 640 routed-down blocks (gy=8)
#define NUPGEMM (NSHUP + NRTUP)     // 1152 GEMM blocks in up_merged
#define NW2F4  (E_*D_*H_/4)         // 4,194,304 float4 in w2
#define NS2F4  (D_*SH_/4)           //   524,288 float4 in shared_w2
#define CVT2W2 (NW2F4/4096)         // 1024 cvt blocks (4096 f4/block)
#define CVT2S2 (NS2F4/4096)         //  128 cvt blocks
#define NCVT2  (CVT2W2 + CVT2S2)    // 1152 trailing cvt blocks in up_merged

typedef unsigned short u16;
typedef __attribute__((ext_vector_type(8))) __bf16 bf16x8;
typedef __attribute__((ext_vector_type(4))) float  f32x4;

struct CvtTable {
  const float* src[5];
  u16*         dst[5];
  int          start[6];   // block-range prefix (blocks of 1024 float4)
};

__device__ __forceinline__ u16 f2bf(float f) {
  union { float f; unsigned int u; } v; v.f = f;
  unsigned int u = v.u;
  return (u16)((u + 0x7fffu + ((u >> 16) & 1u)) >> 16);   // RN-even
}

// async global->LDS, 16B per lane. LDS dest is wave-uniform base + lane*16
// (m104); global src is per-lane (m173) so gather / pre-swizzle is legal.
__device__ __forceinline__ void gload16(const void* g, void* l) {
  __builtin_amdgcn_global_load_lds(
      (const __attribute__((address_space(1))) unsigned int*)g,
      (__attribute__((address_space(3))) unsigned int*)l, 16, 0, 0);
}

// XCD-bijective swizzle over a 1D role range (nb % 8 == 0 for all our roles).
__device__ __forceinline__ int swz8(int b, int nb) {
  return (b & 7) * (nb >> 3) + (b >> 3);
}

// ---------------- mega kernel 1: router blocks + pre-up fp32->bf16 cvt -----
__global__ __launch_bounds__(256) void cvtrouter_k(
    CvtTable ct,
    const float* __restrict__ x, const float* __restrict__ gate_w,
    const float* __restrict__ shared_gate_w,
    int* __restrict__ topk_e, float* __restrict__ topk_w,
    float* __restrict__ sg) {
  __shared__ float xs[RTOK][132];   // +4 pad: rows offset by 4 banks
  __shared__ float lg[RTOK][16];
  __shared__ float sgp[RTOK][16];

  int b   = blockIdx.x;
  int tid = threadIdx.x;

  if (b >= NRBLK) {
    // ---- cvt role: segmented streaming convert, one float4 per thread ----
    int cb = b - NRBLK;
    int s = 0;
    while (cb >= ct.start[s + 1]) s++;       // <=5 uniform iterations
    int i = (cb - ct.start[s]) * 256 + tid;
    float4 f = ((const float4*)ct.src[s])[i];
    ushort4 o; o.x = f2bf(f.x); o.y = f2bf(f.y); o.z = f2bf(f.z); o.w = f2bf(f.w);
    ((ushort4*)ct.dst[s])[i] = o;
    return;
  }

  // ---- router role: 16 tokens/block, thread=(expert,token), fp32 ----
  int e   = tid >> 4;               // 0..15
  int tt  = tid & 15;               // 0..15
  int t0  = b * RTOK;

  float acc = 0.f, sga = 0.f;
  for (int c = 0; c < D_; c += 128) {
    __syncthreads();                // xs reuse from previous chunk done
    #pragma unroll
    for (int i = 0; i < 2; i++) {
      int f = i * 256 + tid;        // 0..511 float4 units, fully coalesced
      int r = f >> 5, c4 = f & 31;
      *(float4*)&xs[r][c4 * 4] =
          *(const float4*)&x[(size_t)(t0 + r) * D_ + c + c4 * 4];
    }
    __syncthreads();
    const float* gw = &gate_w[(size_t)e * D_ + c];
    #pragma unroll
    for (int d4 = 0; d4 < 32; d4++) {
      float4 g  = *(const float4*)&gw[d4 * 4];
      float4 xv = *(const float4*)&xs[tt][d4 * 4];
      acc += xv.x * g.x + xv.y * g.y + xv.z * g.z + xv.w * g.w;
    }
    // shared-gate partial: this thread covers d in [e*8, e*8+8)
    #pragma unroll
    for (int j = 0; j < 8; j += 4) {
      float4 s2 = *(const float4*)&shared_gate_w[c + e * 8 + j];
      float4 xv = *(const float4*)&xs[tt][e * 8 + j];
      sga += xv.x * s2.x + xv.y * s2.y + xv.z * s2.z + xv.w * s2.w;
    }
  }
  lg[tt][e]  = acc;
  sgp[tt][e] = sga;
  __syncthreads();

  if (tid < RTOK) {
    int t = t0 + tid;
    float l[16];
    #pragma unroll
    for (int k = 0; k < 16; k++) l[k] = lg[tid][k];
    int i0 = 0; float l0 = l[0];
    for (int k = 1; k < 16; k++) if (l[k] > l0) { l0 = l[k]; i0 = k; }
    int i1 = -1; float l1 = -3.4e38f;
    for (int k = 0; k < 16; k++) if (k != i0 && l[k] > l1) { l1 = l[k]; i1 = k; }
    float w0 = 1.f / (1.f + expf(l1 - l0));   // == p0/(p0+p1)
    float s = 0.f;
    #pragma unroll
    for (int k = 0; k < 16; k++) s += sgp[tid][k];
    topk_e[2*t] = i0; topk_e[2*t+1] = i1;
    topk_w[2*t] = w0; topk_w[2*t+1] = 1.f - w0;
    sg[t] = 1.f / (1.f + expf(-s));
  }
}

// ---------------- zero-atomic scan + scatter, one block --------------------
__global__ __launch_bounds__(256) void scan_scatter_k(
    const int* __restrict__ topk_e, const float* __restrict__ topk_w,
    int* __restrict__ counts, int* __restrict__ offs,
    int* __restrict__ desc_e, int* __restrict__ desc_m,
    int* __restrict__ tok_of, float* __restrict__ w_of) {
  __shared__ int hc[256][E_];      // 16 KB
  __shared__ int etot[E_];
  int tid = threadIdx.x;
  #pragma unroll
  for (int e = 0; e < E_; e++) hc[tid][e] = 0;
  __syncthreads();

  for (int i = 0; i < 16; i++) {
    int t = tid * 16 + i;
    hc[tid][topk_e[2*t]]++;
    hc[tid][topk_e[2*t+1]]++;
  }
  __syncthreads();

  if (tid < E_) {
    int run = 0;
    for (int k = 0; k < 256; k++) { int c = hc[k][tid]; hc[k][tid] = run; run += c; }
    etot[tid] = run;
  }
  __syncthreads();

  if (tid == 0) {
    int s = 0, n = 0;
    for (int e = 0; e < E_; e++) {
      offs[e] = s; counts[e] = etot[e];
      for (int m0 = 0; m0 < etot[e]; m0 += 128) { desc_e[n] = e; desc_m[n] = m0; n++; }
      s += etot[e];
    }
    offs[E_] = s;
    for (; n < NDESC; n++) { desc_e[n] = -1; desc_m[n] = 0; }
  }
  __syncthreads();

  for (int i = 0; i < 16; i++) {
    int t = tid * 16 + i;
    #pragma unroll
    for (int k = 0; k < TOPK; k++) {
      int e = topk_e[2*t+k];
      int p = hc[tid][e]++;
      int slot = offs[e] + p;
      tok_of[slot] = t;
      w_of[slot]   = topk_w[2*t+k];
    }
  }
}

// ---------------- merged up-projection + W2 cvt tail -----------------------
// 512 threads, 8 waves at 64x32 wave-tiles, VGPR=60 -> request 6 waves/SIMD
// (3 blocks/CU, LDS 3x48=144KB): more co-resident barrier-desynced blocks to
// hide the 2-phase stage+barrier critical path (m114/m233 mechanism).
__global__ __launch_bounds__(512, 6) void up_merged(
    const u16* __restrict__ Xb,
    const u16* __restrict__ sWg, const u16* __restrict__ sW1, u16* __restrict__ sHout,
    const u16* __restrict__ rWg_all, const u16* __restrict__ rW1_all, u16* __restrict__ rHout,
    const float* __restrict__ w2f, u16* __restrict__ wb2,
    const float* __restrict__ s2f, u16* __restrict__ sb2,
    const int* __restrict__ tok_of,
    const int* __restrict__ offs, const int* __restrict__ counts,
    const int* __restrict__ desc_e, const int* __restrict__ desc_m) {
  int bid = blockIdx.x;
  int tid = threadIdx.x;
  if (bid >= NUPGEMM) {
    // ---- cvt role: 8 float4 per thread (4096 f4/block), fully coalesced ----
    int cb = bid - NUPGEMM;
    const float4* src; ushort4* dst; int base;
    if (cb < CVT2W2) { src = (const float4*)w2f; dst = (ushort4*)wb2; base = cb * 4096; }
    else             { src = (const float4*)s2f; dst = (ushort4*)sb2; base = (cb - CVT2W2) * 4096; }
    #pragma unroll
    for (int i = 0; i < 8; i++) {
      int idx = base + i * 512 + tid;
      float4 f = src[idx];
      ushort4 o; o.x = f2bf(f.x); o.y = f2bf(f.y); o.z = f2bf(f.z); o.w = f2bf(f.w);
      dst[idx] = o;
    }
    return;
  }

  const u16 *Wg, *W1; u16* Hout; int Hdim;
  int m0, cnt, pbase, n0;
  const int* tof;
  if (bid < NSHUP) {                        // shared-expert role (gy = 16)
    int l = swz8(bid, NSHUP);
    int bx = l >> 4, by = l & 15;
    m0 = bx * 128; cnt = NTOK; pbase = 0; tof = nullptr;
    Wg = sWg; W1 = sW1; Hout = sHout; Hdim = SH_;
    n0 = by * 128;
  } else {                                  // routed role (gy = 8)
    int r = bid - NSHUP;
    int l = swz8(r, NRTUP);
    int bx = l >> 3, by = l & 7;
    int e = desc_e[bx];
    if (e < 0) return;
    m0 = desc_m[bx]; cnt = counts[e]; pbase = offs[e]; tof = tok_of;
    Wg = rWg_all + (size_t)e * H_ * D_;
    W1 = rW1_all + (size_t)e * H_ * D_;
    Hout = rHout; Hdim = H_;
    n0 = by * 128;
  }

  __shared__ u16 smem[2 * 3 * 4096];   // [buf][A,G,U][128*BK]  48KB

  int lane = tid & 63, wave = tid >> 6;      // 8 waves
  int wm = wave & 1, wn = wave >> 1;         // 2 x 4 wave grid, tile 64x32
  int l16 = lane & 15, quad = lane >> 4;

  // staging: lane tid covers LDS row sr = tid>>2, quad qs = tid&3 (linear).
  // Source column is inverse-swizzled so a swizzled READ sees the right data.
  int sr = tid >> 2;            // 0..127
  int qs = tid & 3;
  int sc = ((qs ^ ((sr >> 1) & 3))) * 8;   // swizzled source col (elements)

  int gm = m0 + sr; if (gm >= cnt) gm = cnt - 1;
  int tok = tof ? tof[pbase + gm] : gm;
  const u16* pa = Xb + (size_t)tok * D_ + sc;
  const u16* pg = Wg + (size_t)(n0 + sr) * D_ + sc;
  const u16* pu = W1 + (size_t)(n0 + sr) * D_ + sc;

  int lbase = wave * 512;   // u16 units: wave*1024B within an operand tile

  f32x4 accg[4][2], accu[4][2];
  f32x4 zero = {0.f, 0.f, 0.f, 0.f};
  #pragma unroll
  for (int i = 0; i < 4; i++)
    #pragma unroll
    for (int j = 0; j < 2; j++) { accg[i][j] = zero; accu[i][j] = zero; }

  int qx8 = (quad ^ ((l16 >> 1) & 3)) * 8;   // swizzled read quad (per-lane)

#define STAGE_UP(b) do {                                            \
    u16* s_ = smem + (b) * 12288 + lbase;                           \
    gload16(pa, s_); gload16(pg, s_ + 4096); gload16(pu, s_ + 8192);\
    pa += BK; pg += BK; pu += BK;                                   \
  } while (0)

  STAGE_UP(0);                      // tile 0   (3 loads in flight)
  STAGE_UP(1);                      // tile 1   (6 in flight)
  int buf = 0;
  const int nt = D_ / BK;           // 32

  for (int t = 0; t < nt; ++t) {
    if (t + 1 < nt) asm volatile("s_waitcnt vmcnt(3)" ::: "memory");
    else            asm volatile("s_waitcnt vmcnt(0)" ::: "memory");
    __builtin_amdgcn_s_barrier();          // tile t complete for ALL waves
    __builtin_amdgcn_sched_barrier(0);     // rule #18: no hoist above barrier

    const u16* base = smem + buf * 12288;
    bf16x8 af[4], gf[2], uf[2];
    #pragma unroll
    for (int i = 0; i < 4; i++)
      af[i] = *(const bf16x8*)&base[(wm*64 + i*16 + l16)*BK + qx8];
    #pragma unroll
    for (int j = 0; j < 2; j++) {
      gf[j] = *(const bf16x8*)&base[4096 + (wn*32 + j*16 + l16)*BK + qx8];
      uf[j] = *(const bf16x8*)&base[8192 + (wn*32 + j*16 + l16)*BK + qx8];
    }
    #pragma unroll
    for (int i = 0; i < 4; i++)
      #pragma unroll
      for (int j = 0; j < 2; j++) {
        accg[i][j] = __builtin_amdgcn_mfma_f32_16x16x32_bf16(af[i], gf[j], accg[i][j], 0, 0, 0);
        accu[i][j] = __builtin_amdgcn_mfma_f32_16x16x32_bf16(af[i], uf[j], accu[i][j], 0, 0, 0);
      }

    __builtin_amdgcn_sched_barrier(0);     // reads stay above barrier #2
    __builtin_amdgcn_s_barrier();          // all waves done reading buf
    if (t + 2 < nt) STAGE_UP(buf);         // tile t+2 -> just-freed buffer
    buf ^= 1;
  }
#undef STAGE_UP

  // epilogue: h = u * silu(g)  (C/D map: col=lane&15, row=quad*4+reg — verified)
  #pragma unroll
  for (int i = 0; i < 4; i++) {
    #pragma unroll
    for (int r = 0; r < 4; r++) {
      int m = m0 + wm*64 + i*16 + quad*4 + r;
      if (m < cnt) {
        size_t prow = (size_t)(pbase + m) * Hdim;
        #pragma unroll
        for (int j = 0; j < 2; j++) {
          int n = n0 + wn*32 + j*16 + l16;
          float g = accg[i][j][r];
          float u = accu[i][j][r];
          Hout[prow + n] = f2bf(u * (g / (1.f + __expf(-g))));
        }
      }
    }
  }
}

// ---------------- merged down-projection: shared + routed, both atomic -----
// 512 threads, 8 waves at 64x32 wave-tiles: acc 32 regs -> low VGPR, request
// 6 waves/SIMD (3 blocks/CU, 24 waves/CU -- 2x the 256-thread version).
// LDS 32KB/block, T2 swizzle, depth-2 counted-vmcnt pipeline.
__global__ __launch_bounds__(512, 6) void down_merged(
    const u16* __restrict__ sHbuf, const u16* __restrict__ sW2, const float* __restrict__ sg,
    const u16* __restrict__ rHbuf, const u16* __restrict__ rW2_all, const float* __restrict__ w_of,
    float* __restrict__ out,
    const int* __restrict__ tok_of,
    const int* __restrict__ offs, const int* __restrict__ counts,
    const int* __restrict__ desc_e, const int* __restrict__ desc_m) {
  int bid = blockIdx.x;
  const u16 *Hbuf, *W2; const float* scale;
  int m0, cnt, pbase, n0, K;
  const int* tof;
  if (bid < NSHDN) {                        // shared role: K = SH_ (gy = 8)
    int l = swz8(bid, NSHDN);
    int bx = l >> 3, by = l & 7;
    m0 = bx * 128; cnt = NTOK; pbase = 0; tof = nullptr;
    Hbuf = sHbuf; W2 = sW2; scale = sg; K = SH_;
    n0 = by * 128;
  } else {                                  // routed role: K = H_ (gy = 8)
    int r = bid - NSHDN;
    int l = swz8(r, NRTDN);
    int bx = l >> 3, by = l & 7;
    int e = desc_e[bx];
    if (e < 0) return;
    m0 = desc_m[bx]; cnt = counts[e]; pbase = offs[e]; tof = tok_of;
    Hbuf = rHbuf; W2 = rW2_all + (size_t)e * D_ * H_; scale = w_of; K = H_;
    n0 = by * 128;
  }

  __shared__ u16 smem[2 * 2 * 4096];   // [buf][A,B][128*BK]  32KB

  int tid  = threadIdx.x;
  int lane = tid & 63, wave = tid >> 6;      // 8 waves
  int wm = wave & 1, wn = wave >> 1;         // 2 x 4 grid, wave-tile 64x32
  int l16 = lane & 15, quad = lane >> 4;

  // staging: 512 threads cover one full 128x32 tile per operand.
  int sr = tid >> 2;            // 0..127
  int qs = tid & 3;
  int sc = ((qs ^ ((sr >> 1) & 3))) * 8;

  int gm = m0 + sr; if (gm >= cnt) gm = cnt - 1;
  const u16* pa = Hbuf + (size_t)(pbase + gm) * K + sc;
  const u16* pb = W2 + (size_t)(n0 + sr) * K + sc;

  int lbase = wave * 512;       // u16: wave*1024B within a tile

  f32x4 acc[4][2];
  f32x4 zero = {0.f, 0.f, 0.f, 0.f};
  #pragma unroll
  for (int i = 0; i < 4; i++)
    #pragma unroll
    for (int j = 0; j < 2; j++) acc[i][j] = zero;

  int qx8 = (quad ^ ((l16 >> 1) & 3)) * 8;

#define STAGE_DN(b) do {                                \
    u16* s_ = smem + (b) * 8192 + lbase;                \
    gload16(pa, s_); gload16(pb, s_ + 4096);            \
    pa += BK; pb += BK;                                 \
  } while (0)

  STAGE_DN(0);                      // tile 0 (2 loads in flight)
  STAGE_DN(1);                      // tile 1 (4 in flight)
  int buf = 0;
  const int nt = K / BK;

  for (int t = 0; t < nt; ++t) {
    if (t + 1 < nt) asm volatile("s_waitcnt vmcnt(2)" ::: "memory");
    else            asm volatile("s_waitcnt vmcnt(0)" ::: "memory");
    __builtin_amdgcn_s_barrier();
    __builtin_amdgcn_sched_barrier(0);

    const u16* base = smem + buf * 8192;
    bf16x8 af[4], bfr[2];
    #pragma unroll
    for (int i = 0; i < 4; i++)
      af[i]  = *(const bf16x8*)&base[(wm*64 + i*16 + l16)*BK + qx8];
    #pragma unroll
    for (int j = 0; j < 2; j++)
      bfr[j] = *(const bf16x8*)&base[4096 + (wn*32 + j*16 + l16)*BK + qx8];
    #pragma unroll
    for (int i = 0; i < 4; i++)
      #pragma unroll
      for (int j = 0; j < 2; j++)
        acc[i][j] = __builtin_amdgcn_mfma_f32_16x16x32_bf16(af[i], bfr[j], acc[i][j], 0, 0, 0);

    __builtin_amdgcn_sched_barrier(0);
    __builtin_amdgcn_s_barrier();
    if (t + 2 < nt) STAGE_DN(buf);
    buf ^= 1;
  }
#undef STAGE_DN

  #pragma unroll
  for (int i = 0; i < 4; i++) {
    #pragma unroll
    for (int r = 0; r < 4; r++) {
      int m = m0 + wm*64 + i*16 + quad*4 + r;
      if (m < cnt) {
        int p   = pbase + m;
        int tok = tof ? tof[p] : p;
        float sc2 = scale[p];
        #pragma unroll
        for (int j = 0; j < 2; j++) {
          int n = n0 + wn*32 + j*16 + l16;
          atomicAdd(&out[(size_t)tok * D_ + n], sc2 * acc[i][j][r]);
        }
      }
    }
  }
}

extern "C" void kernel_launch(void* const* d_in, const int* in_sizes, int n_in,
                              void* d_out, int out_size, void* d_ws, size_t ws_size,
                              hipStream_t stream) {
  const float* x      = (const float*)d_in[0];
  const float* gate_w = (const float*)d_in[1];
  const float* w_gate = (const float*)d_in[2];
  const float* w1     = (const float*)d_in[3];
  const float* w2     = (const float*)d_in[4];
  const float* sh_wg  = (const float*)d_in[5];
  const float* sh_w1  = (const float*)d_in[6];
  const float* sh_w2  = (const float*)d_in[7];
  const float* sh_gw  = (const float*)d_in[8];
  float* out = (float*)d_out;

  char* ws = (char*)d_ws;
  size_t off = 0;
  u16* xb    = (u16*)(ws + off); off += (size_t)NTOK * D_ * 2;
  u16* h_exp = (u16*)(ws + off); off += (size_t)NTOK * TOPK * H_ * 2;
  u16* h_sh  = (u16*)(ws + off); off += (size_t)NTOK * SH_ * 2;
  u16* wb_g  = (u16*)(ws + off); off += (size_t)E_ * H_ * D_ * 2;
  u16* wb_1  = (u16*)(ws + off); off += (size_t)E_ * H_ * D_ * 2;
  u16* wb_2  = (u16*)(ws + off); off += (size_t)E_ * D_ * H_ * 2;
  u16* sb_g  = (u16*)(ws + off); off += (size_t)SH_ * D_ * 2;
  u16* sb_1  = (u16*)(ws + off); off += (size_t)SH_ * D_ * 2;
  u16* sb_2  = (u16*)(ws + off); off += (size_t)D_ * SH_ * 2;
  int*   tok_of = (int*)  (ws + off); off += NTOK * TOPK * 4;
  float* w_of   = (float*)(ws + off); off += NTOK * TOPK * 4;
  float* sg     = (float*)(ws + off); off += NTOK * 4;
  int*   topk_e = (int*)  (ws + off); off += NTOK * TOPK * 4;
  float* topk_w = (float*)(ws + off); off += NTOK * TOPK * 4;
  int*   counts = (int*)  (ws + off); off += 64;
  int*   offs   = (int*)  (ws + off); off += 128;
  int*   fill   = (int*)  (ws + off); off += 64;   // unused (kept for layout)
  int*   desc_e = (int*)  (ws + off); off += NDESC * 4;
  int*   desc_m = (int*)  (ws + off); off += NDESC * 4;

  hipMemsetAsync(out, 0, (size_t)NTOK * D_ * 4, stream);  // both downs atomic

  // cvt segment table in 1024-float4 blocks:
  CvtTable ct;
  const float* srcs[5] = {x, w_gate, w1, sh_wg, sh_w1};
  u16*         dsts[5] = {xb, wb_g, wb_1, sb_g, sb_1};
  int          nblk[5] = {NTOK*D_/1024, E_*H_*D_/1024, E_*H_*D_/1024,
                          SH_*D_/1024, SH_*D_/1024};
  int s = 0;
  for (int i = 0; i < 5; i++) { ct.src[i] = srcs[i]; ct.dst[i] = dsts[i];
                                ct.start[i] = s; s += nblk[i]; }
  ct.start[5] = s;

  cvtrouter_k<<<dim3(NRBLK + s), 256, 0, stream>>>(
      ct, x, gate_w, sh_gw, topk_e, topk_w, sg);
  scan_scatter_k<<<dim3(1), 256, 0, stream>>>(
      topk_e, topk_w, counts, offs, desc_e, desc_m, tok_of, w_of);

  up_merged<<<dim3(NUPGEMM + NCVT2), 512, 0, stream>>>(
      xb, sb_g, sb_1, h_sh, wb_g, wb_1, h_exp,
      w2, wb_2, sh_w2, sb_2,
      tok_of, offs, counts, desc_e, desc_m);
  down_merged<<<dim3(NSHDN + NRTDN), 512, 0, stream>>>(
      h_sh, sb_2, sg, h_exp, wb_2, w_of, out,
      tok_of, offs, counts, desc_e, desc_m);

  (void)in_sizes; (void)n_in; (void)ws_size; (void)fill;
}

// Round 8
// 422.575 us; speedup vs baseline: 2.1722x; 2.1722x over previous
//
#include <hip/hip_runtime.h>
#include <stdint.h>

#define E_    16
#define TOPK  2
#define D_    1024
#define H_    1024
#define SH_   2048
#define NTOK  4096
#define BK    32      // K-step (u16 elements); tile rows are 64B
#define NDESC 80      // max expert chunks: 8192/128 + 16 partials
#define RTOK  16      // router tokens per block
#define NRBLK (NTOK / RTOK)         // 256 router blocks
#define NSHUP (NTOK/128 * SH_/128)  // 512 shared-up blocks (gy=16)
#define NRTUP (NDESC * H_/128)      // 640 routed-up blocks (gy=8)
#define NSHDN (NTOK/128 * D_/128)   // 256 shared-down blocks (gy=8)
#define NRTDN (NDESC * D_/128)      // 640 routed-down blocks (gy=8)
#define NUPGEMM (NSHUP + NRTUP)     // 1152 GEMM blocks in up_merged
#define NW2F4  (E_*D_*H_/4)         // 4,194,304 float4 in w2
#define NS2F4  (D_*SH_/4)           //   524,288 float4 in shared_w2
#define CVT2W2 (NW2F4/4096)         // 1024 cvt blocks (4096 f4/block)
#define CVT2S2 (NS2F4/4096)         //  128 cvt blocks
#define NCVT2  (CVT2W2 + CVT2S2)    // 1152 trailing cvt blocks in up_merged

typedef unsigned short u16;
typedef __attribute__((ext_vector_type(8))) __bf16 bf16x8;
typedef __attribute__((ext_vector_type(4))) float  f32x4;

struct CvtTable {
  const float* src[5];
  u16*         dst[5];
  int          start[6];   // block-range prefix (blocks of 1024 float4)
};

__device__ __forceinline__ u16 f2bf(float f) {
  union { float f; unsigned int u; } v; v.f = f;
  unsigned int u = v.u;
  return (u16)((u + 0x7fffu + ((u >> 16) & 1u)) >> 16);   // RN-even
}

// async global->LDS, 16B per lane. LDS dest is wave-uniform base + lane*16
// (m104); global src is per-lane (m173) so gather / pre-swizzle is legal.
__device__ __forceinline__ void gload16(const void* g, void* l) {
  __builtin_amdgcn_global_load_lds(
      (const __attribute__((address_space(1))) unsigned int*)g,
      (__attribute__((address_space(3))) unsigned int*)l, 16, 0, 0);
}

// XCD-bijective swizzle over a 1D role range (nb % 8 == 0 for all our roles).
__device__ __forceinline__ int swz8(int b, int nb) {
  return (b & 7) * (nb >> 3) + (b >> 3);
}

// ---------------- mega kernel 1: router blocks + pre-up fp32->bf16 cvt -----
__global__ __launch_bounds__(256) void cvtrouter_k(
    CvtTable ct,
    const float* __restrict__ x, const float* __restrict__ gate_w,
    const float* __restrict__ shared_gate_w,
    int* __restrict__ topk_e, float* __restrict__ topk_w,
    float* __restrict__ sg) {
  __shared__ float xs[RTOK][132];   // +4 pad: rows offset by 4 banks
  __shared__ float lg[RTOK][16];
  __shared__ float sgp[RTOK][16];

  int b   = blockIdx.x;
  int tid = threadIdx.x;

  if (b >= NRBLK) {
    // ---- cvt role: segmented streaming convert, one float4 per thread ----
    int cb = b - NRBLK;
    int s = 0;
    while (cb >= ct.start[s + 1]) s++;       // <=5 uniform iterations
    int i = (cb - ct.start[s]) * 256 + tid;
    float4 f = ((const float4*)ct.src[s])[i];
    ushort4 o; o.x = f2bf(f.x); o.y = f2bf(f.y); o.z = f2bf(f.z); o.w = f2bf(f.w);
    ((ushort4*)ct.dst[s])[i] = o;
    return;
  }

  // ---- router role: 16 tokens/block, thread=(expert,token), fp32 ----
  int e   = tid >> 4;               // 0..15
  int tt  = tid & 15;               // 0..15
  int t0  = b * RTOK;

  float acc = 0.f, sga = 0.f;
  for (int c = 0; c < D_; c += 128) {
    __syncthreads();                // xs reuse from previous chunk done
    #pragma unroll
    for (int i = 0; i < 2; i++) {
      int f = i * 256 + tid;        // 0..511 float4 units, fully coalesced
      int r = f >> 5, c4 = f & 31;
      *(float4*)&xs[r][c4 * 4] =
          *(const float4*)&x[(size_t)(t0 + r) * D_ + c + c4 * 4];
    }
    __syncthreads();
    const float* gw = &gate_w[(size_t)e * D_ + c];
    #pragma unroll
    for (int d4 = 0; d4 < 32; d4++) {
      float4 g  = *(const float4*)&gw[d4 * 4];
      float4 xv = *(const float4*)&xs[tt][d4 * 4];
      acc += xv.x * g.x + xv.y * g.y + xv.z * g.z + xv.w * g.w;
    }
    // shared-gate partial: this thread covers d in [e*8, e*8+8)
    #pragma unroll
    for (int j = 0; j < 8; j += 4) {
      float4 s2 = *(const float4*)&shared_gate_w[c + e * 8 + j];
      float4 xv = *(const float4*)&xs[tt][e * 8 + j];
      sga += xv.x * s2.x + xv.y * s2.y + xv.z * s2.z + xv.w * s2.w;
    }
  }
  lg[tt][e]  = acc;
  sgp[tt][e] = sga;
  __syncthreads();

  if (tid < RTOK) {
    int t = t0 + tid;
    float l[16];
    #pragma unroll
    for (int k = 0; k < 16; k++) l[k] = lg[tid][k];
    int i0 = 0; float l0 = l[0];
    for (int k = 1; k < 16; k++) if (l[k] > l0) { l0 = l[k]; i0 = k; }
    int i1 = -1; float l1 = -3.4e38f;
    for (int k = 0; k < 16; k++) if (k != i0 && l[k] > l1) { l1 = l[k]; i1 = k; }
    float w0 = 1.f / (1.f + expf(l1 - l0));   // == p0/(p0+p1)
    float s = 0.f;
    #pragma unroll
    for (int k = 0; k < 16; k++) s += sgp[tid][k];
    topk_e[2*t] = i0; topk_e[2*t+1] = i1;
    topk_w[2*t] = w0; topk_w[2*t+1] = 1.f - w0;
    sg[t] = 1.f / (1.f + expf(-s));
  }
}

// ---------------- zero-atomic scan + scatter, one block --------------------
__global__ __launch_bounds__(256) void scan_scatter_k(
    const int* __restrict__ topk_e, const float* __restrict__ topk_w,
    int* __restrict__ counts, int* __restrict__ offs,
    int* __restrict__ desc_e, int* __restrict__ desc_m,
    int* __restrict__ tok_of, float* __restrict__ w_of) {
  __shared__ int hc[256][E_];      // 16 KB
  __shared__ int etot[E_];
  int tid = threadIdx.x;
  #pragma unroll
  for (int e = 0; e < E_; e++) hc[tid][e] = 0;
  __syncthreads();

  for (int i = 0; i < 16; i++) {
    int t = tid * 16 + i;
    hc[tid][topk_e[2*t]]++;
    hc[tid][topk_e[2*t+1]]++;
  }
  __syncthreads();

  if (tid < E_) {
    int run = 0;
    for (int k = 0; k < 256; k++) { int c = hc[k][tid]; hc[k][tid] = run; run += c; }
    etot[tid] = run;
  }
  __syncthreads();

  if (tid == 0) {
    int s = 0, n = 0;
    for (int e = 0; e < E_; e++) {
      offs[e] = s; counts[e] = etot[e];
      for (int m0 = 0; m0 < etot[e]; m0 += 128) { desc_e[n] = e; desc_m[n] = m0; n++; }
      s += etot[e];
    }
    offs[E_] = s;
    for (; n < NDESC; n++) { desc_e[n] = -1; desc_m[n] = 0; }
  }
  __syncthreads();

  for (int i = 0; i < 16; i++) {
    int t = tid * 16 + i;
    #pragma unroll
    for (int k = 0; k < TOPK; k++) {
      int e = topk_e[2*t+k];
      int p = hc[tid][e]++;
      int slot = offs[e] + p;
      tok_of[slot] = t;
      w_of[slot]   = topk_w[2*t+k];
    }
  }
}

// ---------------- merged up-projection + W2 cvt tail -----------------------
// 512 thr / 8 waves / 64x32 wave-tiles, launch_bounds(512,4) [R7 lesson: a
// tighter bound caps VGPR below the ~60 the kernel needs -> scratch spill].
// NEW: 3-buffer, ONE barrier per K-step. Ledger: at iter t every wave passed
// barrier(t-1), whose ARRIVAL implies all reads of tile t-2 completed; and
// STAGE(t+1) targets buf[(t+1)%3] which held exactly tile t-2. Counted
// vmcnt(3) covers own tile-t loads; loads cross barriers (T4).
__global__ __launch_bounds__(512, 4) void up_merged(
    const u16* __restrict__ Xb,
    const u16* __restrict__ sWg, const u16* __restrict__ sW1, u16* __restrict__ sHout,
    const u16* __restrict__ rWg_all, const u16* __restrict__ rW1_all, u16* __restrict__ rHout,
    const float* __restrict__ w2f, u16* __restrict__ wb2,
    const float* __restrict__ s2f, u16* __restrict__ sb2,
    const int* __restrict__ tok_of,
    const int* __restrict__ offs, const int* __restrict__ counts,
    const int* __restrict__ desc_e, const int* __restrict__ desc_m) {
  int bid = blockIdx.x;
  int tid = threadIdx.x;
  if (bid >= NUPGEMM) {
    // ---- cvt role: 8 float4 per thread (4096 f4/block), fully coalesced ----
    int cb = bid - NUPGEMM;
    const float4* src; ushort4* dst; int base;
    if (cb < CVT2W2) { src = (const float4*)w2f; dst = (ushort4*)wb2; base = cb * 4096; }
    else             { src = (const float4*)s2f; dst = (ushort4*)sb2; base = (cb - CVT2W2) * 4096; }
    #pragma unroll
    for (int i = 0; i < 8; i++) {
      int idx = base + i * 512 + tid;
      float4 f = src[idx];
      ushort4 o; o.x = f2bf(f.x); o.y = f2bf(f.y); o.z = f2bf(f.z); o.w = f2bf(f.w);
      dst[idx] = o;
    }
    return;
  }

  const u16 *Wg, *W1; u16* Hout; int Hdim;
  int m0, cnt, pbase, n0;
  const int* tof;
  if (bid < NSHUP) {                        // shared-expert role (gy = 16)
    int l = swz8(bid, NSHUP);
    int bx = l >> 4, by = l & 15;
    m0 = bx * 128; cnt = NTOK; pbase = 0; tof = nullptr;
    Wg = sWg; W1 = sW1; Hout = sHout; Hdim = SH_;
    n0 = by * 128;
  } else {                                  // routed role (gy = 8)
    int r = bid - NSHUP;
    int l = swz8(r, NRTUP);
    int bx = l >> 3, by = l & 7;
    int e = desc_e[bx];
    if (e < 0) return;
    m0 = desc_m[bx]; cnt = counts[e]; pbase = offs[e]; tof = tok_of;
    Wg = rWg_all + (size_t)e * H_ * D_;
    W1 = rW1_all + (size_t)e * H_ * D_;
    Hout = rHout; Hdim = H_;
    n0 = by * 128;
  }

  __shared__ u16 smem[3 * 3 * 4096];   // [buf0..2][A,G,U][128*BK]  72KB

  int lane = tid & 63, wave = tid >> 6;      // 8 waves
  int wm = wave & 1, wn = wave >> 1;         // 2 x 4 wave grid, tile 64x32
  int l16 = lane & 15, quad = lane >> 4;

  // staging: lane tid covers LDS row sr = tid>>2, quad qs = tid&3 (linear).
  // Source column is inverse-swizzled so a swizzled READ sees the right data.
  int sr = tid >> 2;            // 0..127
  int qs = tid & 3;
  int sc = ((qs ^ ((sr >> 1) & 3))) * 8;   // swizzled source col (elements)

  int gm = m0 + sr; if (gm >= cnt) gm = cnt - 1;
  int tok = tof ? tof[pbase + gm] : gm;
  const u16* pa = Xb + (size_t)tok * D_ + sc;
  const u16* pg = Wg + (size_t)(n0 + sr) * D_ + sc;
  const u16* pu = W1 + (size_t)(n0 + sr) * D_ + sc;

  int lbase = wave * 512;   // u16 units: wave*1024B within an operand tile

  f32x4 accg[4][2], accu[4][2];
  f32x4 zero = {0.f, 0.f, 0.f, 0.f};
  #pragma unroll
  for (int i = 0; i < 4; i++)
    #pragma unroll
    for (int j = 0; j < 2; j++) { accg[i][j] = zero; accu[i][j] = zero; }

  int qx8 = (quad ^ ((l16 >> 1) & 3)) * 8;   // swizzled read quad (per-lane)

#define STAGE_UP(b) do {                                            \
    u16* s_ = smem + (b) * 12288 + lbase;                           \
    gload16(pa, s_); gload16(pg, s_ + 4096); gload16(pu, s_ + 8192);\
    pa += BK; pg += BK; pu += BK;                                   \
  } while (0)

  STAGE_UP(0);                      // tile 0 into buf 0
  int cur = 0;
  const int nt = D_ / BK;           // 32

  for (int t = 0; t < nt; ++t) {
    int nx = (cur == 2) ? 0 : cur + 1;
    if (t + 1 < nt) {
      STAGE_UP(nx);                                      // tile t+1
      asm volatile("s_waitcnt vmcnt(3)" ::: "memory");   // tile t landed
    } else {
      asm volatile("s_waitcnt vmcnt(0)" ::: "memory");
    }
    __builtin_amdgcn_s_barrier();          // everyone's tile-t loads landed
    __builtin_amdgcn_sched_barrier(0);     // rule #18: no hoist above barrier

    const u16* base = smem + cur * 12288;
    bf16x8 af[4], gf[2], uf[2];
    #pragma unroll
    for (int i = 0; i < 4; i++)
      af[i] = *(const bf16x8*)&base[(wm*64 + i*16 + l16)*BK + qx8];
    #pragma unroll
    for (int j = 0; j < 2; j++) {
      gf[j] = *(const bf16x8*)&base[4096 + (wn*32 + j*16 + l16)*BK + qx8];
      uf[j] = *(const bf16x8*)&base[8192 + (wn*32 + j*16 + l16)*BK + qx8];
    }
    #pragma unroll
    for (int i = 0; i < 4; i++)
      #pragma unroll
      for (int j = 0; j < 2; j++) {
        accg[i][j] = __builtin_amdgcn_mfma_f32_16x16x32_bf16(af[i], gf[j], accg[i][j], 0, 0, 0);
        accu[i][j] = __builtin_amdgcn_mfma_f32_16x16x32_bf16(af[i], uf[j], accu[i][j], 0, 0, 0);
      }
    __builtin_amdgcn_sched_barrier(0);     // reads complete before next stage
    cur = nx;
  }
#undef STAGE_UP

  // epilogue: h = u * silu(g)  (C/D map: col=lane&15, row=quad*4+reg — verified)
  #pragma unroll
  for (int i = 0; i < 4; i++) {
    #pragma unroll
    for (int r = 0; r < 4; r++) {
      int m = m0 + wm*64 + i*16 + quad*4 + r;
      if (m < cnt) {
        size_t prow = (size_t)(pbase + m) * Hdim;
        #pragma unroll
        for (int j = 0; j < 2; j++) {
          int n = n0 + wn*32 + j*16 + l16;
          float g = accg[i][j][r];
          float u = accu[i][j][r];
          Hout[prow + n] = f2bf(u * (g / (1.f + __expf(-g))));
        }
      }
    }
  }
}

// ---------------- merged down-projection: shared + routed, both atomic -----
// 512 thr / 8 waves / 64x32 wave-tiles (acc 32 regs), launch_bounds(512,4).
// Same 3-buffer 1-barrier pipeline; vmcnt(2) = own tile-t loads (2/STAGE).
__global__ __launch_bounds__(512, 4) void down_merged(
    const u16* __restrict__ sHbuf, const u16* __restrict__ sW2, const float* __restrict__ sg,
    const u16* __restrict__ rHbuf, const u16* __restrict__ rW2_all, const float* __restrict__ w_of,
    float* __restrict__ out,
    const int* __restrict__ tok_of,
    const int* __restrict__ offs, const int* __restrict__ counts,
    const int* __restrict__ desc_e, const int* __restrict__ desc_m) {
  int bid = blockIdx.x;
  const u16 *Hbuf, *W2; const float* scale;
  int m0, cnt, pbase, n0, K;
  const int* tof;
  if (bid < NSHDN) {                        // shared role: K = SH_ (gy = 8)
    int l = swz8(bid, NSHDN);
    int bx = l >> 3, by = l & 7;
    m0 = bx * 128; cnt = NTOK; pbase = 0; tof = nullptr;
    Hbuf = sHbuf; W2 = sW2; scale = sg; K = SH_;
    n0 = by * 128;
  } else {                                  // routed role: K = H_ (gy = 8)
    int r = bid - NSHDN;
    int l = swz8(r, NRTDN);
    int bx = l >> 3, by = l & 7;
    int e = desc_e[bx];
    if (e < 0) return;
    m0 = desc_m[bx]; cnt = counts[e]; pbase = offs[e]; tof = tok_of;
    Hbuf = rHbuf; W2 = rW2_all + (size_t)e * D_ * H_; scale = w_of; K = H_;
    n0 = by * 128;
  }

  __shared__ u16 smem[3 * 2 * 4096];   // [buf0..2][A,B][128*BK]  48KB

  int tid  = threadIdx.x;
  int lane = tid & 63, wave = tid >> 6;      // 8 waves
  int wm = wave & 1, wn = wave >> 1;         // 2 x 4 grid, wave-tile 64x32
  int l16 = lane & 15, quad = lane >> 4;

  // staging: 512 threads cover one full 128x32 tile per operand.
  int sr = tid >> 2;            // 0..127
  int qs = tid & 3;
  int sc = ((qs ^ ((sr >> 1) & 3))) * 8;

  int gm = m0 + sr; if (gm >= cnt) gm = cnt - 1;
  const u16* pa = Hbuf + (size_t)(pbase + gm) * K + sc;
  const u16* pb = W2 + (size_t)(n0 + sr) * K + sc;

  int lbase = wave * 512;       // u16: wave*1024B within a tile

  f32x4 acc[4][2];
  f32x4 zero = {0.f, 0.f, 0.f, 0.f};
  #pragma unroll
  for (int i = 0; i < 4; i++)
    #pragma unroll
    for (int j = 0; j < 2; j++) acc[i][j] = zero;

  int qx8 = (quad ^ ((l16 >> 1) & 3)) * 8;

#define STAGE_DN(b) do {                                \
    u16* s_ = smem + (b) * 8192 + lbase;                \
    gload16(pa, s_); gload16(pb, s_ + 4096);            \
    pa += BK; pb += BK;                                 \
  } while (0)

  STAGE_DN(0);                      // tile 0 into buf 0
  int cur = 0;
  const int nt = K / BK;

  for (int t = 0; t < nt; ++t) {
    int nx = (cur == 2) ? 0 : cur + 1;
    if (t + 1 < nt) {
      STAGE_DN(nx);                                      // tile t+1
      asm volatile("s_waitcnt vmcnt(2)" ::: "memory");   // tile t landed
    } else {
      asm volatile("s_waitcnt vmcnt(0)" ::: "memory");
    }
    __builtin_amdgcn_s_barrier();
    __builtin_amdgcn_sched_barrier(0);

    const u16* base = smem + cur * 8192;
    bf16x8 af[4], bfr[2];
    #pragma unroll
    for (int i = 0; i < 4; i++)
      af[i]  = *(const bf16x8*)&base[(wm*64 + i*16 + l16)*BK + qx8];
    #pragma unroll
    for (int j = 0; j < 2; j++)
      bfr[j] = *(const bf16x8*)&base[4096 + (wn*32 + j*16 + l16)*BK + qx8];
    #pragma unroll
    for (int i = 0; i < 4; i++)
      #pragma unroll
      for (int j = 0; j < 2; j++)
        acc[i][j] = __builtin_amdgcn_mfma_f32_16x16x32_bf16(af[i], bfr[j], acc[i][j], 0, 0, 0);
    __builtin_amdgcn_sched_barrier(0);
    cur = nx;
  }
#undef STAGE_DN

  #pragma unroll
  for (int i = 0; i < 4; i++) {
    #pragma unroll
    for (int r = 0; r < 4; r++) {
      int m = m0 + wm*64 + i*16 + quad*4 + r;
      if (m < cnt) {
        int p   = pbase + m;
        int tok = tof ? tof[p] : p;
        float sc2 = scale[p];
        #pragma unroll
        for (int j = 0; j < 2; j++) {
          int n = n0 + wn*32 + j*16 + l16;
          atomicAdd(&out[(size_t)tok * D_ + n], sc2 * acc[i][j][r]);
        }
      }
    }
  }
}

extern "C" void kernel_launch(void* const* d_in, const int* in_sizes, int n_in,
                              void* d_out, int out_size, void* d_ws, size_t ws_size,
                              hipStream_t stream) {
  const float* x      = (const float*)d_in[0];
  const float* gate_w = (const float*)d_in[1];
  const float* w_gate = (const float*)d_in[2];
  const float* w1     = (const float*)d_in[3];
  const float* w2     = (const float*)d_in[4];
  const float* sh_wg  = (const float*)d_in[5];
  const float* sh_w1  = (const float*)d_in[6];
  const float* sh_w2  = (const float*)d_in[7];
  const float* sh_gw  = (const float*)d_in[8];
  float* out = (float*)d_out;

  char* ws = (char*)d_ws;
  size_t off = 0;
  u16* xb    = (u16*)(ws + off); off += (size_t)NTOK * D_ * 2;
  u16* h_exp = (u16*)(ws + off); off += (size_t)NTOK * TOPK * H_ * 2;
  u16* h_sh  = (u16*)(ws + off); off += (size_t)NTOK * SH_ * 2;
  u16* wb_g  = (u16*)(ws + off); off += (size_t)E_ * H_ * D_ * 2;
  u16* wb_1  = (u16*)(ws + off); off += (size_t)E_ * H_ * D_ * 2;
  u16* wb_2  = (u16*)(ws + off); off += (size_t)E_ * D_ * H_ * 2;
  u16* sb_g  = (u16*)(ws + off); off += (size_t)SH_ * D_ * 2;
  u16* sb_1  = (u16*)(ws + off); off += (size_t)SH_ * D_ * 2;
  u16* sb_2  = (u16*)(ws + off); off += (size_t)D_ * SH_ * 2;
  int*   tok_of = (int*)  (ws + off); off += NTOK * TOPK * 4;
  float* w_of   = (float*)(ws + off); off += NTOK * TOPK * 4;
  float* sg     = (float*)(ws + off); off += NTOK * 4;
  int*   topk_e = (int*)  (ws + off); off += NTOK * TOPK * 4;
  float* topk_w = (float*)(ws + off); off += NTOK * TOPK * 4;
  int*   counts = (int*)  (ws + off); off += 64;
  int*   offs   = (int*)  (ws + off); off += 128;
  int*   fill   = (int*)  (ws + off); off += 64;   // unused (kept for layout)
  int*   desc_e = (int*)  (ws + off); off += NDESC * 4;
  int*   desc_m = (int*)  (ws + off); off += NDESC * 4;

  hipMemsetAsync(out, 0, (size_t)NTOK * D_ * 4, stream);  // both downs atomic

  // cvt segment table in 1024-float4 blocks:
  CvtTable ct;
  const float* srcs[5] = {x, w_gate, w1, sh_wg, sh_w1};
  u16*         dsts[5] = {xb, wb_g, wb_1, sb_g, sb_1};
  int          nblk[5] = {NTOK*D_/1024, E_*H_*D_/1024, E_*H_*D_/1024,
                          SH_*D_/1024, SH_*D_/1024};
  int s = 0;
  for (int i = 0; i < 5; i++) { ct.src[i] = srcs[i]; ct.dst[i] = dsts[i];
                                ct.start[i] = s; s += nblk[i]; }
  ct.start[5] = s;

  cvtrouter_k<<<dim3(NRBLK + s), 256, 0, stream>>>(
      ct, x, gate_w, sh_gw, topk_e, topk_w, sg);
  scan_scatter_k<<<dim3(1), 256, 0, stream>>>(
      topk_e, topk_w, counts, offs, desc_e, desc_m, tok_of, w_of);

  up_merged<<<dim3(NUPGEMM + NCVT2), 512, 0, stream>>>(
      xb, sb_g, sb_1, h_sh, wb_g, wb_1, h_exp,
      w2, wb_2, sh_w2, sb_2,
      tok_of, offs, counts, desc_e, desc_m);
  down_merged<<<dim3(NSHDN + NRTDN), 512, 0, stream>>>(
      h_sh, sb_2, sg, h_exp, wb_2, w_of, out,
      tok_of, offs, counts, desc_e, desc_m);

  (void)in_sizes; (void)n_in; (void)ws_size; (void)fill;
}